// Round 12
// baseline (816.399 us; speedup 1.0000x reference)
//
#include <hip/hip_runtime.h>
#include <hip/hip_bf16.h>
#include <hip/hip_cooperative_groups.h>

namespace cg = cooperative_groups;

#define NDIM 128
#define MROWS 32           // rows per block (two 16-row MFMA tiles)
#define BTHREADS 512       // 8 waves per block
#define SCAN_CHUNK 1024    // fallback scan: per block 256 threads x 4 elements
#define COOP_G 1024        // cooperative build grid (4 blocks/CU guaranteed)

typedef __attribute__((ext_vector_type(8))) short short8;
typedef __attribute__((ext_vector_type(4))) float f32x4;

__device__ __forceinline__ float bf2f(__hip_bfloat16 v) { return __bfloat162float(v); }

__device__ __forceinline__ float ldf(const void* p, long i, int f32) {
    return f32 ? ((const float*)p)[i] : bf2f(((const __hip_bfloat16*)p)[i]);
}
__device__ __forceinline__ void stf(void* p, long i, int f32, float v) {
    if (f32) ((float*)p)[i] = v;
    else     ((__hip_bfloat16*)p)[i] = __float2bfloat16(v);
}
__device__ __forceinline__ short f2bf(float v) {
    __hip_bfloat16 h = __float2bfloat16(v);
    short s;
    __builtin_memcpy(&s, &h, 2);
    return s;
}
// bf16x2 packed in a uint: low halfword = even feature, high = odd feature
__device__ __forceinline__ float bflo(unsigned u) { u <<= 16; float f; __builtin_memcpy(&f, &u, 4); return f; }
__device__ __forceinline__ float bfhi(unsigned u) { u &= 0xffff0000u; float f; __builtin_memcpy(&f, &u, 4); return f; }
__device__ __forceinline__ unsigned packbf(float a, float b) {
    unsigned la = (unsigned short)f2bf(a);
    unsigned hb = (unsigned short)f2bf(b);
    return (hb << 16) | la;
}
// Swizzled LDS index (shorts) for A-tiles: 16B-chunk XOR by (row&7).
__device__ __forceinline__ int aswz(int m, int k) {
    return m * NDIM + ((((k >> 3) ^ (m & 7)) << 3) | (k & 7));
}
// Same swizzle at uint (bf16x2) granularity: p = feature-pair index 0..63.
__device__ __forceinline__ int wswz(int m, int p) {
    return m * 64 + ((((p >> 2) ^ (m & 7)) << 2) | (p & 3));
}

// asm-pinned gather load: result VGPR stays allocated and the load cannot be
// sunk into its consumer (R5-R8: every source-level pipeline collapsed;
// VGPR=32 proved it). R9/R11 verified this structure passing at 75us.
#define GLOAD(dst, sa, voff)                                              \
    asm volatile("global_load_dword %0, %1, %2"                           \
                 : "=v"(dst) : "v"(voff), "s"(sa) : "memory")

// ---- device helper: per-block dtype detection (2KB L2-broadcast reads) -----
__device__ __forceinline__ void detect_flags(const int* xedge, const void* x,
                                             int* s_se, int* s_sc,
                                             int* e64_out, int* wf_out) {
    const int t = threadIdx.x;
    if (t == 0) { *s_se = 1; *s_sc = 0; }
    __syncthreads();
    for (int i = t; i < 512; i += 256)
        if (xedge[2 * i + 1] != 0) *s_se = 0;
    {
        const unsigned short* xh = (const unsigned short*)x;
        int c = 0;
        for (int i = t; i < 1024; i += 256) {
            int ex = (xh[2 * i] >> 7) & 0xFF;
            if (ex >= 100 && ex <= 150) c++;
        }
        atomicAdd(s_sc, c);
    }
    __syncthreads();
    *e64_out = *s_se;
    *wf_out = (*s_sc < 900) ? 1 : 0;
}

// ======================= COOPERATIVE BUILD (primary path) ===================
// One kernel replaces {memset, prep, scan_partial, scan_scatter, fill}.
// Phases: A zero+detect+transpose -> B count -> C scan -> D fill, separated
// by grid.sync(). Cross-phase scalars (cnt, gpart) use device-scope atomics
// for cross-XCD safety (G16); rowptr/col are consumed by LATER KERNELS only
// (kernel-boundary flush makes plain stores safe).

__global__ __launch_bounds__(256, 4)
void coop_build(const void* __restrict__ x,
                const void* __restrict__ W1l, const void* __restrict__ b1l,
                const void* __restrict__ W1r, const void* __restrict__ W2l,
                const void* __restrict__ b2l, const void* __restrict__ W2r,
                const void* __restrict__ Wd,
                short* __restrict__ T1l, short* __restrict__ T1r,
                short* __restrict__ T2l, short* __restrict__ T2r,
                short* __restrict__ Td, float* __restrict__ b1c,
                float* __restrict__ b2c, unsigned* __restrict__ xb,
                const int* __restrict__ xedge, int E,
                int* __restrict__ cnt, int N,
                int* __restrict__ flags, float* __restrict__ accum,
                int* __restrict__ npos, int* __restrict__ donecnt,
                int* __restrict__ gpart, int* __restrict__ rowptr,
                int* __restrict__ col, const unsigned int* __restrict__ yw) {
    cg::grid_group grid = cg::this_grid();
    const int t = threadIdx.x;
    const int b = blockIdx.x;
    const long gid = (long)b * 256 + t;
    const long gstride = (long)gridDim.x * 256;

    __shared__ int s_se, s_sc;
    int e64, wf;
    detect_flags(xedge, x, &s_se, &s_sc, &e64, &wf);
    if (b == 0) {
        if (t == 0) {
            flags[0] = e64; flags[2] = wf;
            atomicExch((int*)&accum[0], 0);
            atomicExch((int*)&accum[1], 0);
            atomicExch(npos, 0);
            atomicExch(donecnt, 0);
        }
        __shared__ int s_sy;
        if (t == 0) s_sy = 0;
        __syncthreads();
        for (int i = t; i < 1024; i += 256)
            if (yw[i] > 1u) s_sy = 1;
        __syncthreads();
        if (t == 0) flags[1] = s_sy;
    }
    // ---- phase A: zero cnt (atomicExch: no dirty-L2 hazard vs phase B
    //      atomics), weight transpose, optional x conversion ----
    for (long i = gid; i < N; i += gstride) atomicExch(&cnt[i], 0);
    for (long i = gid; i < NDIM * NDIM; i += gstride) {
        int k = (int)(i >> 7), n = (int)(i & 127);
        int o = n * NDIM + k;
        T1l[o] = f2bf(ldf(W1l, i, wf));
        T1r[o] = f2bf(ldf(W1r, i, wf));
        T2l[o] = f2bf(ldf(W2l, i, wf));
        T2r[o] = f2bf(ldf(W2r, i, wf));
        Td [o] = f2bf(ldf(Wd , i, wf));
        if (i < NDIM) { b1c[i] = ldf(b1l, i, wf); b2c[i] = ldf(b2l, i, wf); }
    }
    if (wf) {
        const long np = (long)N * 64;
        for (long p = gid; p < np; p += gstride) {
            float2 v = ((const float2*)x)[p];
            xb[p] = packbf(v.x, v.y);
        }
    }
    grid.sync();
    // ---- phase B: degree count ----
    for (long e = gid; e < E; e += gstride) {
        int d = e64 ? xedge[2 * (E + e)] : xedge[E + e];
        atomicAdd(&cnt[d], 1);
    }
    grid.sync();
    // ---- phase C: exclusive scan (block chunks + cross-block prefix) ----
    const int C = (N + gridDim.x - 1) / gridDim.x;  // <=1024 for N<=1M @ G=1024
    __shared__ int red[256];
    __shared__ int sc_[1024];
    {
        int s = 0;
        for (int i = t; i < C; i += 256) {
            long idx = (long)b * C + i;
            if (idx < N) s += atomicAdd(&cnt[idx], 0);
        }
        red[t] = s;
        __syncthreads();
        for (int off = 128; off >= 1; off >>= 1) {
            if (t < off) red[t] += red[t + off];
            __syncthreads();
        }
        if (t == 0) atomicExch(&gpart[b], red[0]);
    }
    grid.sync();
    {
        int sown = 0;
        for (int i = t; i < b; i += 256) sown += atomicAdd(&gpart[i], 0);
        red[t] = sown;
        __syncthreads();
        for (int off = 128; off >= 1; off >>= 1) {
            if (t < off) red[t] += red[t + off];
            __syncthreads();
        }
        const int base = red[0];
        for (int i = t; i < C; i += 256) {
            long idx = (long)b * C + i;
            sc_[i] = (idx < N) ? atomicAdd(&cnt[idx], 0) : 0;
        }
        __syncthreads();
        if (t == 0) {
            int run = base;
            for (int i = 0; i < C; ++i) {
                long idx = (long)b * C + i;
                if (idx < N) {
                    rowptr[idx] = run;              // consumed by later kernels
                    atomicExch(&cnt[idx], run);     // cursor for phase D
                    run += sc_[i];
                }
            }
        }
        if (b == 0 && t == 0) rowptr[N] = E;
    }
    grid.sync();
    // ---- phase D: fill CSR col ----
    for (long e = gid; e < E; e += gstride) {
        int s_ = e64 ? xedge[2 * e] : xedge[e];
        int d  = e64 ? xedge[2 * (E + e)] : xedge[E + e];
        int p = atomicAdd(&cnt[d], 1);
        col[p] = s_;
    }
}

// ======================= FALLBACK PATH (R11, verified) ======================

__global__ void prep_kernel(const void* __restrict__ x,
                            const void* __restrict__ W1l, const void* __restrict__ b1l,
                            const void* __restrict__ W1r, const void* __restrict__ W2l,
                            const void* __restrict__ b2l, const void* __restrict__ W2r,
                            const void* __restrict__ Wd,
                            short* __restrict__ T1l, short* __restrict__ T1r,
                            short* __restrict__ T2l, short* __restrict__ T2r,
                            short* __restrict__ Td, float* __restrict__ b1c,
                            float* __restrict__ b2c, unsigned* __restrict__ xb,
                            const int* __restrict__ xedge, int E,
                            int* __restrict__ cnt, int N,
                            int* __restrict__ flags) {
    __shared__ int s_se, s_sc;
    const int t = threadIdx.x;
    int e64, wf;
    detect_flags(xedge, x, &s_se, &s_sc, &e64, &wf);
    if (blockIdx.x == 0 && t == 0) { flags[0] = e64; flags[2] = wf; }
    const long idx = (long)blockIdx.x * 256 + t;
    if (idx < E) {
        int d = e64 ? xedge[2 * (E + idx)] : xedge[E + idx];
        atomicAdd(&cnt[d], 1);
    }
    if (idx < NDIM * NDIM) {
        int k = (int)(idx >> 7), n = (int)(idx & 127);
        int o = n * NDIM + k;
        T1l[o] = f2bf(ldf(W1l, idx, wf));
        T1r[o] = f2bf(ldf(W1r, idx, wf));
        T2l[o] = f2bf(ldf(W2l, idx, wf));
        T2r[o] = f2bf(ldf(W2r, idx, wf));
        Td [o] = f2bf(ldf(Wd , idx, wf));
        if (idx < NDIM) { b1c[idx] = ldf(b1l, idx, wf); b2c[idx] = ldf(b2l, idx, wf); }
    }
    if (wf) {
        const long np = (long)N * 64;
        const long stride = (long)gridDim.x * 256;
        for (long pidx = idx; pidx < np; pidx += stride) {
            float2 v = ((const float2*)x)[pidx];
            xb[pidx] = packbf(v.x, v.y);
        }
    }
}

__global__ void scan_partial(const int* __restrict__ cnt, int* __restrict__ bsum, int N,
                             const unsigned int* __restrict__ yw,
                             int* __restrict__ flags) {
    __shared__ int red[256];
    const int t = threadIdx.x;
    if (blockIdx.x == 0) {
        __shared__ int s_sy;
        if (t == 0) s_sy = 0;
        __syncthreads();
        for (int i = t; i < 1024; i += 256)
            if (yw[i] > 1u) s_sy = 1;
        __syncthreads();
        if (t == 0) flags[1] = s_sy;
    }
    const long base = (long)blockIdx.x * SCAN_CHUNK + (long)t * 4;
    int s = 0;
#pragma unroll
    for (int i = 0; i < 4; ++i) { long idx = base + i; if (idx < N) s += cnt[idx]; }
    red[t] = s;
    __syncthreads();
    for (int off = 128; off >= 1; off >>= 1) {
        if (t < off) red[t] += red[t + off];
        __syncthreads();
    }
    if (t == 0) bsum[blockIdx.x] = red[0];
}

__global__ void scan_scatter(int* __restrict__ cnt, const int* __restrict__ bsum,
                             int* __restrict__ rowptr, int N) {
    __shared__ int tsum[256];
    __shared__ int red[256];
    const int t = threadIdx.x;
    const long base = (long)blockIdx.x * SCAN_CHUNK + (long)t * 4;
    int loc[4];
    int s = 0;
#pragma unroll
    for (int i = 0; i < 4; ++i) {
        long idx = base + i;
        int c = (idx < N) ? cnt[idx] : 0;
        loc[i] = s;
        s += c;
    }
    tsum[t] = s;
    int sown = 0;
    for (int i = t; i < blockIdx.x; i += 256) sown += bsum[i];
    red[t] = sown;
    __syncthreads();
    for (int off = 1; off < 256; off <<= 1) {
        int u = (t >= off) ? tsum[t - off] : 0;
        __syncthreads();
        tsum[t] += u;
        __syncthreads();
    }
    for (int off = 128; off >= 1; off >>= 1) {
        if (t < off) red[t] += red[t + off];
        __syncthreads();
    }
    const int b0 = red[0];
    const int texcl = tsum[t] - s;
#pragma unroll
    for (int i = 0; i < 4; ++i) {
        long idx = base + i;
        if (idx < N) {
            int v = b0 + texcl + loc[i];
            rowptr[idx] = v;
            cnt[idx] = v;   // cursor seed for fill
        }
    }
    if (blockIdx.x == gridDim.x - 1 && t == 255) rowptr[N] = b0 + tsum[255];
}

__global__ void fill_kernel(const int* __restrict__ xedge, int E,
                            const int* __restrict__ flags,
                            int* __restrict__ cur, int* __restrict__ col) {
    int e = blockIdx.x * blockDim.x + threadIdx.x;
    if (e >= E) return;
    const int e64 = flags[0];
    int s = e64 ? xedge[2 * e] : xedge[e];
    int d = e64 ? xedge[2 * (E + e)] : xedge[E + e];
    int p = atomicAdd(&cur[d], 1);
    col[p] = s;
}

// ---- SAGE layer (R9/R11 verified body; layer2 additionally folds finalize
// via device done-counter). Gather: deg-gated groups of 8 asm-pinned loads,
// ONE vmcnt(0) per row, pass-through asm, exact masked-add tree.

template <bool RELU, int OUTMODE>
__global__ __launch_bounds__(BTHREADS, 2)
void layer_mfma(const unsigned* __restrict__ Xb, const unsigned* __restrict__ Xraw,
                const int* __restrict__ rowptr,
                const int* __restrict__ col, const short* __restrict__ WlT,
                const float* __restrict__ biasc, const short* __restrict__ WrT,
                const short* __restrict__ WdT, const void* __restrict__ yv,
                const int* __restrict__ flags, void* __restrict__ outp,
                float* __restrict__ accum, int* __restrict__ npos,
                int* __restrict__ donecnt, int N) {
    __shared__ short AS[2 * MROWS * NDIM];  // [Ms 8KB][Ss 8KB]
    __shared__ int ylds[MROWS];
    __shared__ float redm[8][2];
    short* Ms = AS;
    short* Ss = AS + MROWS * NDIM;
    unsigned* Msw = (unsigned*)Ms;
    unsigned* Ssw = (unsigned*)Ss;
    const int t = threadIdx.x;
    const int n0 = blockIdx.x * MROWS;
    const int wf = flags[2];
    const unsigned* __restrict__ X = wf ? Xb : Xraw;

    if (OUTMODE == 1 && t < MROWS) {
        const int yb = flags[1];
        int n = n0 + t;
        int yn = -1;
        if (n < N)
            yn = yb ? (int)((const unsigned char*)yv)[n]
                    : (((const int*)yv)[n] != 0 ? 1 : 0);
        ylds[t] = yn;
    }

    // ---- gather: 8 row-groups (one wave each), 4 rows/wave ------------------
    {
        const int p = t & 63;
        const unsigned voff = (unsigned)(p * 4);
        const unsigned long long Xb64 = (unsigned long long)(uintptr_t)X;
        const int g = __builtin_amdgcn_readfirstlane(t >> 6);
        int r = g;
        int b = 0, e = 0;
        {
            int n = n0 + r;
            if (n < N) {
                b = __builtin_amdgcn_readfirstlane(rowptr[n]);
                e = __builtin_amdgcn_readfirstlane(rowptr[n + 1]);
            }
        }
        for (int it = 0; it < 4; ++it, r += 8) {
            const int n = n0 + r;
            const int deg = e - b;
            const int* colb = col + b;
            int cs[32];
            if (deg > 0) {
#pragma unroll
                for (int j = 0; j < 8; ++j) {
                    int c = __builtin_amdgcn_readfirstlane(colb[j]);
                    cs[j] = ((unsigned)c >= (unsigned)N) ? 0 : c;
                }
            }
            if (deg > 8) {
#pragma unroll
                for (int j = 8; j < 16; ++j) {
                    int c = __builtin_amdgcn_readfirstlane(colb[j]);
                    cs[j] = ((unsigned)c >= (unsigned)N) ? 0 : c;
                }
            }
            if (deg > 16) {
#pragma unroll
                for (int j = 16; j < 24; ++j) {
                    int c = __builtin_amdgcn_readfirstlane(colb[j]);
                    cs[j] = ((unsigned)c >= (unsigned)N) ? 0 : c;
                }
            }
            if (deg > 24) {
#pragma unroll
                for (int j = 24; j < 32; ++j) {
                    int c = __builtin_amdgcn_readfirstlane(colb[j]);
                    cs[j] = ((unsigned)c >= (unsigned)N) ? 0 : c;
                }
            }
            // rowptr prefetch consumed BEFORE the asm window (R9 hygiene fix)
            int bn = 0, en = 0;
            if (it < 3) {
                int nn = n0 + r + 8;
                if (nn < N) {
                    bn = __builtin_amdgcn_readfirstlane(rowptr[nn]);
                    en = __builtin_amdgcn_readfirstlane(rowptr[nn + 1]);
                }
            }
            unsigned u[32];
            unsigned su = 0;
            if (n < N) {
                unsigned long long sa = Xb64 + ((unsigned long long)(unsigned)n << 8);
                GLOAD(su, sa, voff);
            }
            if (deg > 0) {
#pragma unroll
                for (int j = 0; j < 8; ++j) {
                    unsigned long long sa = Xb64 + ((unsigned long long)(unsigned)cs[j] << 8);
                    GLOAD(u[j], sa, voff);
                }
            }
            if (deg > 8) {
#pragma unroll
                for (int j = 8; j < 16; ++j) {
                    unsigned long long sa = Xb64 + ((unsigned long long)(unsigned)cs[j] << 8);
                    GLOAD(u[j], sa, voff);
                }
            }
            if (deg > 16) {
#pragma unroll
                for (int j = 16; j < 24; ++j) {
                    unsigned long long sa = Xb64 + ((unsigned long long)(unsigned)cs[j] << 8);
                    GLOAD(u[j], sa, voff);
                }
            }
            if (deg > 24) {
#pragma unroll
                for (int j = 24; j < 32; ++j) {
                    unsigned long long sa = Xb64 + ((unsigned long long)(unsigned)cs[j] << 8);
                    GLOAD(u[j], sa, voff);
                }
            }
            asm volatile("s_waitcnt vmcnt(0)" ::: "memory");
            __builtin_amdgcn_sched_barrier(0);
            if (n < N) asm volatile("" : "+v"(su));
            if (deg > 0) {
#pragma unroll
                for (int j = 0; j < 8; ++j) asm volatile("" : "+v"(u[j]));
            }
            if (deg > 8) {
#pragma unroll
                for (int j = 8; j < 16; ++j) asm volatile("" : "+v"(u[j]));
            }
            if (deg > 16) {
#pragma unroll
                for (int j = 16; j < 24; ++j) asm volatile("" : "+v"(u[j]));
            }
            if (deg > 24) {
#pragma unroll
                for (int j = 24; j < 32; ++j) asm volatile("" : "+v"(u[j]));
            }
            float m0 = 0.f, m1 = 0.f;
            if (deg > 0) {
                float p0 = 0.f, p1 = 0.f, p2 = 0.f, p3 = 0.f;
                float q0 = 0.f, q1 = 0.f, q2 = 0.f, q3 = 0.f;
#pragma unroll
                for (int j = 0; j < 32; j += 4) {
                    if (j + 0 < deg) { p0 += bflo(u[j]);     q0 += bfhi(u[j]); }
                    if (j + 1 < deg) { p1 += bflo(u[j + 1]); q1 += bfhi(u[j + 1]); }
                    if (j + 2 < deg) { p2 += bflo(u[j + 2]); q2 += bfhi(u[j + 2]); }
                    if (j + 3 < deg) { p3 += bflo(u[j + 3]); q3 += bfhi(u[j + 3]); }
                }
                m0 = (p0 + p1) + (p2 + p3);
                m1 = (q0 + q1) + (q2 + q3);
                for (int i = b + 32; i < e; ++i) {  // rare tail (deg > 32)
                    int c = __builtin_amdgcn_readfirstlane(col[i]);
                    unsigned uu = X[(long)c * 64 + p];
                    m0 += bflo(uu);
                    m1 += bfhi(uu);
                }
                float inv = 1.f / (float)deg;
                m0 *= inv; m1 *= inv;
            }
            int wi = wswz(r, p);
            Msw[wi] = packbf(m0, m1);
            Ssw[wi] = su;
            b = bn; e = en;
        }
    }
    __syncthreads();
    // ---- MFMA: wave w owns cols [w*16, w*16+16), 2x1 16x16x32 tiles ----
    const int l = t & 63, w = t >> 6;
    const int quad = l >> 4, l15 = l & 15;
    const int wcol = w * 16;
    f32x4 acc[2] = {};
    for (int k0 = 0; k0 < NDIM; k0 += 32) {
        const int kc = k0 + quad * 8;
        short8 ams[2], ass[2], bl, br;
#pragma unroll
        for (int rt = 0; rt < 2; ++rt) {
            int m = rt * 16 + l15;
            ams[rt] = *(const short8*)&Ms[aswz(m, kc)];
            ass[rt] = *(const short8*)&Ss[aswz(m, kc)];
        }
        {
            int n = wcol + l15;
            bl = *(const short8*)&WlT[n * NDIM + kc];
            br = *(const short8*)&WrT[n * NDIM + kc];
        }
#pragma unroll
        for (int rt = 0; rt < 2; ++rt) {
            acc[rt] = __builtin_amdgcn_mfma_f32_16x16x32_bf16(
                ams[rt], bl, acc[rt], 0, 0, 0);
            acc[rt] = __builtin_amdgcn_mfma_f32_16x16x32_bf16(
                ass[rt], br, acc[rt], 0, 0, 0);
        }
    }
    __syncthreads();  // all MFMA LDS reads done; Ms/Ss reusable

    if (OUTMODE == 0) {
        {
            int cg = wcol + l15;
            float bv = biasc[cg];
#pragma unroll
            for (int rt = 0; rt < 2; ++rt)
#pragma unroll
                for (int reg = 0; reg < 4; ++reg) {
                    int row = rt * 16 + quad * 4 + reg;
                    float v = acc[rt][reg] + bv;
                    if (RELU) v = fmaxf(v, 0.f);
                    Ms[row * NDIM + cg] = f2bf(v);
                }
        }
        __syncthreads();
        unsigned* ob = (unsigned*)outp;
        for (int idx = t; idx < MROWS * 64; idx += BTHREADS) {
            int r = idx >> 6;
            if (n0 + r < N) ob[(long)n0 * 64 + idx] = Msw[idx];
        }
    } else {
        {
            int cg = wcol + l15;
            float bv = biasc[cg];
#pragma unroll
            for (int rt = 0; rt < 2; ++rt)
#pragma unroll
                for (int reg = 0; reg < 4; ++reg) {
                    int row = rt * 16 + quad * 4 + reg;
                    float v = acc[rt][reg] + bv;
                    Ms[aswz(row, cg)] = f2bf(v);
                    int n = n0 + row;
                    if (n < N) {
                        if (wf) ((float*)outp)[1 + (long)n * NDIM + cg] = v;
                        else ((__hip_bfloat16*)outp)[1 + (long)n * NDIM + cg] =
                                 __float2bfloat16(v);
                    }
                }
        }
        __syncthreads();
        // ---- decoder GEMM from Abf(Ms) ----
        f32x4 acc2[2] = {};
        for (int k0 = 0; k0 < NDIM; k0 += 32) {
            const int kc = k0 + quad * 8;
            short8 a[2], bwd;
#pragma unroll
            for (int rt = 0; rt < 2; ++rt)
                a[rt] = *(const short8*)&Ms[aswz(rt * 16 + l15, kc)];
            bwd = *(const short8*)&WdT[(wcol + l15) * NDIM + kc];
#pragma unroll
            for (int rt = 0; rt < 2; ++rt)
                acc2[rt] = __builtin_amdgcn_mfma_f32_16x16x32_bf16(
                    a[rt], bwd, acc2[rt], 0, 0, 0);
        }
        float lpos = 0.f, lneg = 0.f;
#pragma unroll
        for (int rt = 0; rt < 2; ++rt)
#pragma unroll
            for (int reg = 0; reg < 4; ++reg) {
                int row = rt * 16 + quad * 4 + reg;
                int yn = ylds[row];
                if (yn >= 0) {
                    float z = acc2[rt][reg];
                    float L = log1pf(expf(-fabsf(z)));
                    if (yn) lpos += fmaxf(-z, 0.f) + L;   // softplus(-z)
                    else    lneg += fmaxf(z, 0.f) + L;    // softplus(z)
                }
            }
#pragma unroll
        for (int off = 32; off >= 1; off >>= 1) {
            lpos += __shfl_down(lpos, off, 64);
            lneg += __shfl_down(lneg, off, 64);
        }
        if (l == 0) { redm[w][0] = lpos; redm[w][1] = lneg; }
        __syncthreads();
        if (t == 0) {
            float sp = 0.f, sn = 0.f;
#pragma unroll
            for (int i = 0; i < 8; ++i) { sp += redm[i][0]; sn += redm[i][1]; }
            atomicAdd(&accum[0], sp);
            atomicAdd(&accum[1], sn);
            int c = 0;
            for (int i = 0; i < MROWS; ++i) if (ylds[i] > 0) c++;
            if (c) atomicAdd(npos, c);
            // ---- folded finalize: last block computes the loss ----
            __threadfence();
            unsigned d = (unsigned)atomicAdd(donecnt, 1);
            if (d == (unsigned)(gridDim.x - 1)) {
                float spT = atomicAdd(&accum[0], 0.f);   // coherent reads
                float snT = atomicAdd(&accum[1], 0.f);
                int npv = atomicAdd(npos, 0);
                float np_ = (float)npv;
                float nn_ = (float)N - np_;
                float l2v = spT / (fmaxf(np_, 1.f) * 128.f);
                float l1v = snT / (fmaxf(nn_, 1.f) * 128.f);
                stf(outp, 0, wf, l1v + l2v);
            }
        }
    }
}

// ---- launch ----------------------------------------------------------------

extern "C" void kernel_launch(void* const* d_in, const int* in_sizes, int n_in,
                              void* d_out, int out_size, void* d_ws, size_t ws_size,
                              hipStream_t stream) {
    const void* x    = d_in[0];
    const int* xedge = (const int*)d_in[1];
    const void* y    = d_in[2];
    const void* W1l  = d_in[4];
    const void* b1l  = d_in[5];
    const void* W1r  = d_in[6];
    const void* W2l  = d_in[7];
    const void* b2l  = d_in[8];
    const void* W2r  = d_in[9];
    const void* Wdec = d_in[10];

    const int N = in_sizes[0] / NDIM;
    const int E = in_sizes[1] / 2;

    char* ws = (char*)d_ws;
    size_t off = 0;
    auto alloc = [&](size_t bytes) -> void* {
        void* p = ws + off;
        off = (off + bytes + 255) & ~(size_t)255;
        return p;
    };
    int*   flags  = (int*)alloc(64);
    // cnt | accum | npos | donecnt consecutive: fallback zeroes with ONE memset
    int*   cnt    = (int*)alloc((size_t)N * 4);
    float* accum  = (float*)alloc(64);
    int*   npos   = (int*)alloc(64);
    int*   donecnt= (int*)alloc(64);
    int*   gpart  = (int*)alloc((size_t)COOP_G * 4);   // coop scan partials
    int*   rowptr = (int*)alloc((size_t)(N + 1) * 4);
    int*   col    = (int*)alloc((size_t)E * 4);
    unsigned* xb  = (unsigned*)alloc((size_t)N * 64 * 4);
    unsigned* hbuf = (unsigned*)alloc((size_t)N * 64 * 4);
    short* T1l = (short*)alloc(NDIM * NDIM * 2);
    short* T1r = (short*)alloc(NDIM * NDIM * 2);
    short* T2l = (short*)alloc(NDIM * NDIM * 2);
    short* T2r = (short*)alloc(NDIM * NDIM * 2);
    short* Td  = (short*)alloc(NDIM * NDIM * 2);
    float* b1c = (float*)alloc(NDIM * 4);
    float* b2c = (float*)alloc(NDIM * 4);

    // ---- primary: one cooperative build kernel (zero+prep+scan+fill) ----
    bool coop_ok = (N <= COOP_G * 1024);
    if (coop_ok) {
        const void* xv = x;
        int Ev = E, Nv = N;
        void* args[] = {
            (void*)&xv, (void*)&W1l, (void*)&b1l, (void*)&W1r, (void*)&W2l,
            (void*)&b2l, (void*)&W2r, (void*)&Wdec,
            (void*)&T1l, (void*)&T1r, (void*)&T2l, (void*)&T2r, (void*)&Td,
            (void*)&b1c, (void*)&b2c, (void*)&xb, (void*)&xedge, (void*)&Ev,
            (void*)&cnt, (void*)&Nv, (void*)&flags, (void*)&accum,
            (void*)&npos, (void*)&donecnt, (void*)&gpart, (void*)&rowptr,
            (void*)&col, (void*)&y };
        hipError_t err = hipLaunchCooperativeKernel(
            (const void*)coop_build, dim3(COOP_G), dim3(256), args, 0, stream);
        if (err != hipSuccess) coop_ok = false;
    }
    if (!coop_ok) {
        // ---- fallback: verified R11 multi-kernel path ----
        const size_t zlen = (((size_t)N * 4 + 255) & ~(size_t)255) + 3 * 256;
        hipMemsetAsync(cnt, 0, zlen, stream);   // cnt+accum+npos+donecnt
        const long prep_items = (E > NDIM * NDIM) ? E : NDIM * NDIM;
        prep_kernel<<<(int)((prep_items + 255) / 256), 256, 0, stream>>>(
            x, W1l, b1l, W1r, W2l, b2l, W2r, Wdec,
            T1l, T1r, T2l, T2r, Td, b1c, b2c, xb, xedge, E, cnt, N, flags);
        const int sb = (N + SCAN_CHUNK - 1) / SCAN_CHUNK;
        scan_partial<<<sb, 256, 0, stream>>>(cnt, gpart, N,
                                             (const unsigned int*)y, flags);
        scan_scatter<<<sb, 256, 0, stream>>>(cnt, gpart, rowptr, N);
        const int eb = (E + 255) / 256;
        fill_kernel<<<eb, 256, 0, stream>>>(xedge, E, flags, cnt, col);
    }

    const int nbM = (N + MROWS - 1) / MROWS;
    // layer 1: reads xb (f32-converted) or x directly (bf16), writes hbuf
    layer_mfma<true, 0><<<nbM, BTHREADS, 0, stream>>>(
        xb, (const unsigned*)x, rowptr, col, T1l, b1c, T1r, nullptr, nullptr,
        flags, hbuf, nullptr, nullptr, nullptr, N);
    // layer 2 (fused): reads hbuf, writes d_out emb + loss (finalize folded)
    layer_mfma<false, 1><<<nbM, BTHREADS, 0, stream>>>(
        hbuf, hbuf, rowptr, col, T2l, b2c, T2r, Td, y, flags,
        d_out, accum, npos, donecnt, N);
}

// Round 14
// 341.001 us; speedup vs baseline: 2.3941x; 2.3941x over previous
//
#include <hip/hip_runtime.h>
#include <hip/hip_bf16.h>

#define NDIM 128
#define MROWS 32           // rows per block (two 16-row MFMA tiles)
#define BTHREADS 512       // 8 waves per block
#define SCAN_CHUNK 1024    // scan: per block 256 threads x 4 elements

typedef __attribute__((ext_vector_type(8))) short short8;
typedef __attribute__((ext_vector_type(4))) float f32x4;

__device__ __forceinline__ float bf2f(__hip_bfloat16 v) { return __bfloat162float(v); }

__device__ __forceinline__ float ldf(const void* p, long i, int f32) {
    return f32 ? ((const float*)p)[i] : bf2f(((const __hip_bfloat16*)p)[i]);
}
__device__ __forceinline__ void stf(void* p, long i, int f32, float v) {
    if (f32) ((float*)p)[i] = v;
    else     ((__hip_bfloat16*)p)[i] = __float2bfloat16(v);
}
__device__ __forceinline__ short f2bf(float v) {
    __hip_bfloat16 h = __float2bfloat16(v);
    short s;
    __builtin_memcpy(&s, &h, 2);
    return s;
}
// bf16x2 packed in a uint: low halfword = even feature, high = odd feature
__device__ __forceinline__ float bflo(unsigned u) { u <<= 16; float f; __builtin_memcpy(&f, &u, 4); return f; }
__device__ __forceinline__ float bfhi(unsigned u) { u &= 0xffff0000u; float f; __builtin_memcpy(&f, &u, 4); return f; }
__device__ __forceinline__ unsigned packbf(float a, float b) {
    unsigned la = (unsigned short)f2bf(a);
    unsigned hb = (unsigned short)f2bf(b);
    return (hb << 16) | la;
}
// Swizzled LDS index (shorts) for A-tiles: 16B-chunk XOR by (row&7).
__device__ __forceinline__ int aswz(int m, int k) {
    return m * NDIM + ((((k >> 3) ^ (m & 7)) << 3) | (k & 7));
}
// Same swizzle at uint (bf16x2) granularity: p = feature-pair index 0..63.
__device__ __forceinline__ int wswz(int m, int p) {
    return m * 64 + ((((p >> 2) ^ (m & 7)) << 2) | (p & 3));
}

// asm-pinned gather load: result VGPR stays allocated and the load cannot be
// sunk into its consumer (R5-R8: every source-level pipeline collapsed;
// VGPR=32 proved it). R9/R11 verified this structure passing at 75us.
#define GLOAD(dst, sa, voff)                                              \
    asm volatile("global_load_dword %0, %1, %2"                           \
                 : "=v"(dst) : "v"(voff), "s"(sa) : "memory")

// ---- device helper: per-block dtype detection (2KB L2-broadcast reads) -----
__device__ __forceinline__ void detect_flags(const int* xedge, const void* x,
                                             int* s_se, int* s_sc,
                                             int* e64_out, int* wf_out) {
    const int t = threadIdx.x;
    if (t == 0) { *s_se = 1; *s_sc = 0; }
    __syncthreads();
    for (int i = t; i < 512; i += 256)
        if (xedge[2 * i + 1] != 0) *s_se = 0;
    {
        const unsigned short* xh = (const unsigned short*)x;
        int c = 0;
        for (int i = t; i < 1024; i += 256) {
            int ex = (xh[2 * i] >> 7) & 0xFF;
            if (ex >= 100 && ex <= 150) c++;
        }
        atomicAdd(s_sc, c);
    }
    __syncthreads();
    *e64_out = *s_se;
    *wf_out = (*s_sc < 900) ? 1 : 0;
}

// ---- prep: per-block dtype detection + weights + biases + degree pass ------
// cnt/accum/npos/donecnt are zeroed by ONE hipMemsetAsync beforehand.

__global__ void prep_kernel(const void* __restrict__ x,
                            const void* __restrict__ W1l, const void* __restrict__ b1l,
                            const void* __restrict__ W1r, const void* __restrict__ W2l,
                            const void* __restrict__ b2l, const void* __restrict__ W2r,
                            const void* __restrict__ Wd,
                            short* __restrict__ T1l, short* __restrict__ T1r,
                            short* __restrict__ T2l, short* __restrict__ T2r,
                            short* __restrict__ Td, float* __restrict__ b1c,
                            float* __restrict__ b2c, unsigned* __restrict__ xb,
                            const int* __restrict__ xedge, int E,
                            int* __restrict__ cnt, int N,
                            int* __restrict__ flags) {
    __shared__ int s_se, s_sc;
    const int t = threadIdx.x;
    int e64, wf;
    detect_flags(xedge, x, &s_se, &s_sc, &e64, &wf);
    if (blockIdx.x == 0 && t == 0) { flags[0] = e64; flags[2] = wf; }
    const long idx = (long)blockIdx.x * 256 + t;
    if (idx < E) {
        int d = e64 ? xedge[2 * (E + idx)] : xedge[E + idx];
        atomicAdd(&cnt[d], 1);
    }
    if (idx < NDIM * NDIM) {
        int k = (int)(idx >> 7), n = (int)(idx & 127);
        int o = n * NDIM + k;
        T1l[o] = f2bf(ldf(W1l, idx, wf));
        T1r[o] = f2bf(ldf(W1r, idx, wf));
        T2l[o] = f2bf(ldf(W2l, idx, wf));
        T2r[o] = f2bf(ldf(W2r, idx, wf));
        Td [o] = f2bf(ldf(Wd , idx, wf));
        if (idx < NDIM) { b1c[idx] = ldf(b1l, idx, wf); b2c[idx] = ldf(b2l, idx, wf); }
    }
    if (wf) {
        const long np = (long)N * 64;
        const long stride = (long)gridDim.x * 256;
        for (long pidx = idx; pidx < np; pidx += stride) {
            float2 v = ((const float2*)x)[pidx];
            xb[pidx] = packbf(v.x, v.y);
        }
    }
}

// ---- 2-kernel exclusive scan (verified R10/R11): partial sums, then
// scatter with self-prefix. y-dtype probe folded into scan_partial block 0.

__global__ void scan_partial(const int* __restrict__ cnt, int* __restrict__ bsum, int N,
                             const unsigned int* __restrict__ yw,
                             int* __restrict__ flags) {
    __shared__ int red[256];
    const int t = threadIdx.x;
    if (blockIdx.x == 0) {
        __shared__ int s_sy;
        if (t == 0) s_sy = 0;
        __syncthreads();
        for (int i = t; i < 1024; i += 256)
            if (yw[i] > 1u) s_sy = 1;
        __syncthreads();
        if (t == 0) flags[1] = s_sy;
    }
    const long base = (long)blockIdx.x * SCAN_CHUNK + (long)t * 4;
    int s = 0;
#pragma unroll
    for (int i = 0; i < 4; ++i) { long idx = base + i; if (idx < N) s += cnt[idx]; }
    red[t] = s;
    __syncthreads();
    for (int off = 128; off >= 1; off >>= 1) {
        if (t < off) red[t] += red[t + off];
        __syncthreads();
    }
    if (t == 0) bsum[blockIdx.x] = red[0];
}

__global__ void scan_scatter(int* __restrict__ cnt, const int* __restrict__ bsum,
                             int* __restrict__ rowptr, int N) {
    __shared__ int tsum[256];
    __shared__ int red[256];
    const int t = threadIdx.x;
    const long base = (long)blockIdx.x * SCAN_CHUNK + (long)t * 4;
    int loc[4];
    int s = 0;
#pragma unroll
    for (int i = 0; i < 4; ++i) {
        long idx = base + i;
        int c = (idx < N) ? cnt[idx] : 0;
        loc[i] = s;
        s += c;
    }
    tsum[t] = s;
    int sown = 0;
    for (int i = t; i < blockIdx.x; i += 256) sown += bsum[i];
    red[t] = sown;
    __syncthreads();
    for (int off = 1; off < 256; off <<= 1) {
        int u = (t >= off) ? tsum[t - off] : 0;
        __syncthreads();
        tsum[t] += u;
        __syncthreads();
    }
    for (int off = 128; off >= 1; off >>= 1) {
        if (t < off) red[t] += red[t + off];
        __syncthreads();
    }
    const int b0 = red[0];
    const int texcl = tsum[t] - s;
#pragma unroll
    for (int i = 0; i < 4; ++i) {
        long idx = base + i;
        if (idx < N) {
            int v = b0 + texcl + loc[i];
            rowptr[idx] = v;
            cnt[idx] = v;   // cursor seed for fill
        }
    }
    if (blockIdx.x == gridDim.x - 1 && t == 255) rowptr[N] = b0 + tsum[255];
}

__global__ void fill_kernel(const int* __restrict__ xedge, int E,
                            const int* __restrict__ flags,
                            int* __restrict__ cur, int* __restrict__ col) {
    int e = blockIdx.x * blockDim.x + threadIdx.x;
    if (e >= E) return;
    const int e64 = flags[0];
    int s = e64 ? xedge[2 * e] : xedge[e];
    int d = e64 ? xedge[2 * (E + e)] : xedge[E + e];
    int p = atomicAdd(&cur[d], 1);
    col[p] = s;
}

// ---- SAGE layer (R9/R11 verified body; layer2 folds finalize via device
// done-counter — verified passing in R12). Gather: deg-gated groups of 8
// asm-pinned loads, ONE vmcnt(0) per row, pass-through asm, exact
// masked-add tree.

template <bool RELU, int OUTMODE>
__global__ __launch_bounds__(BTHREADS, 2)
void layer_mfma(const unsigned* __restrict__ Xb, const unsigned* __restrict__ Xraw,
                const int* __restrict__ rowptr,
                const int* __restrict__ col, const short* __restrict__ WlT,
                const float* __restrict__ biasc, const short* __restrict__ WrT,
                const short* __restrict__ WdT, const void* __restrict__ yv,
                const int* __restrict__ flags, void* __restrict__ outp,
                float* __restrict__ accum, int* __restrict__ npos,
                int* __restrict__ donecnt, int N) {
    __shared__ short AS[2 * MROWS * NDIM];  // [Ms 8KB][Ss 8KB]
    __shared__ int ylds[MROWS];
    __shared__ float redm[8][2];
    short* Ms = AS;
    short* Ss = AS + MROWS * NDIM;
    unsigned* Msw = (unsigned*)Ms;
    unsigned* Ssw = (unsigned*)Ss;
    const int t = threadIdx.x;
    const int n0 = blockIdx.x * MROWS;
    const int wf = flags[2];
    const unsigned* __restrict__ X = wf ? Xb : Xraw;

    if (OUTMODE == 1 && t < MROWS) {
        const int yb = flags[1];
        int n = n0 + t;
        int yn = -1;
        if (n < N)
            yn = yb ? (int)((const unsigned char*)yv)[n]
                    : (((const int*)yv)[n] != 0 ? 1 : 0);
        ylds[t] = yn;
    }

    // ---- gather: 8 row-groups (one wave each), 4 rows/wave ------------------
    {
        const int p = t & 63;
        const unsigned voff = (unsigned)(p * 4);
        const unsigned long long Xb64 = (unsigned long long)(uintptr_t)X;
        const int g = __builtin_amdgcn_readfirstlane(t >> 6);
        int r = g;
        int b = 0, e = 0;
        {
            int n = n0 + r;
            if (n < N) {
                b = __builtin_amdgcn_readfirstlane(rowptr[n]);
                e = __builtin_amdgcn_readfirstlane(rowptr[n + 1]);
            }
        }
        for (int it = 0; it < 4; ++it, r += 8) {
            const int n = n0 + r;
            const int deg = e - b;
            const int* colb = col + b;
            int cs[32];
            if (deg > 0) {
#pragma unroll
                for (int j = 0; j < 8; ++j) {
                    int c = __builtin_amdgcn_readfirstlane(colb[j]);
                    cs[j] = ((unsigned)c >= (unsigned)N) ? 0 : c;
                }
            }
            if (deg > 8) {
#pragma unroll
                for (int j = 8; j < 16; ++j) {
                    int c = __builtin_amdgcn_readfirstlane(colb[j]);
                    cs[j] = ((unsigned)c >= (unsigned)N) ? 0 : c;
                }
            }
            if (deg > 16) {
#pragma unroll
                for (int j = 16; j < 24; ++j) {
                    int c = __builtin_amdgcn_readfirstlane(colb[j]);
                    cs[j] = ((unsigned)c >= (unsigned)N) ? 0 : c;
                }
            }
            if (deg > 24) {
#pragma unroll
                for (int j = 24; j < 32; ++j) {
                    int c = __builtin_amdgcn_readfirstlane(colb[j]);
                    cs[j] = ((unsigned)c >= (unsigned)N) ? 0 : c;
                }
            }
            // rowptr prefetch consumed BEFORE the asm window (R9 hygiene fix)
            int bn = 0, en = 0;
            if (it < 3) {
                int nn = n0 + r + 8;
                if (nn < N) {
                    bn = __builtin_amdgcn_readfirstlane(rowptr[nn]);
                    en = __builtin_amdgcn_readfirstlane(rowptr[nn + 1]);
                }
            }
            unsigned u[32];
            unsigned su = 0;
            if (n < N) {
                unsigned long long sa = Xb64 + ((unsigned long long)(unsigned)n << 8);
                GLOAD(su, sa, voff);
            }
            if (deg > 0) {
#pragma unroll
                for (int j = 0; j < 8; ++j) {
                    unsigned long long sa = Xb64 + ((unsigned long long)(unsigned)cs[j] << 8);
                    GLOAD(u[j], sa, voff);
                }
            }
            if (deg > 8) {
#pragma unroll
                for (int j = 8; j < 16; ++j) {
                    unsigned long long sa = Xb64 + ((unsigned long long)(unsigned)cs[j] << 8);
                    GLOAD(u[j], sa, voff);
                }
            }
            if (deg > 16) {
#pragma unroll
                for (int j = 16; j < 24; ++j) {
                    unsigned long long sa = Xb64 + ((unsigned long long)(unsigned)cs[j] << 8);
                    GLOAD(u[j], sa, voff);
                }
            }
            if (deg > 24) {
#pragma unroll
                for (int j = 24; j < 32; ++j) {
                    unsigned long long sa = Xb64 + ((unsigned long long)(unsigned)cs[j] << 8);
                    GLOAD(u[j], sa, voff);
                }
            }
            asm volatile("s_waitcnt vmcnt(0)" ::: "memory");
            __builtin_amdgcn_sched_barrier(0);
            if (n < N) asm volatile("" : "+v"(su));
            if (deg > 0) {
#pragma unroll
                for (int j = 0; j < 8; ++j) asm volatile("" : "+v"(u[j]));
            }
            if (deg > 8) {
#pragma unroll
                for (int j = 8; j < 16; ++j) asm volatile("" : "+v"(u[j]));
            }
            if (deg > 16) {
#pragma unroll
                for (int j = 16; j < 24; ++j) asm volatile("" : "+v"(u[j]));
            }
            if (deg > 24) {
#pragma unroll
                for (int j = 24; j < 32; ++j) asm volatile("" : "+v"(u[j]));
            }
            float m0 = 0.f, m1 = 0.f;
            if (deg > 0) {
                float p0 = 0.f, p1 = 0.f, p2 = 0.f, p3 = 0.f;
                float q0 = 0.f, q1 = 0.f, q2 = 0.f, q3 = 0.f;
#pragma unroll
                for (int j = 0; j < 32; j += 4) {
                    if (j + 0 < deg) { p0 += bflo(u[j]);     q0 += bfhi(u[j]); }
                    if (j + 1 < deg) { p1 += bflo(u[j + 1]); q1 += bfhi(u[j + 1]); }
                    if (j + 2 < deg) { p2 += bflo(u[j + 2]); q2 += bfhi(u[j + 2]); }
                    if (j + 3 < deg) { p3 += bflo(u[j + 3]); q3 += bfhi(u[j + 3]); }
                }
                m0 = (p0 + p1) + (p2 + p3);
                m1 = (q0 + q1) + (q2 + q3);
                for (int i = b + 32; i < e; ++i) {  // rare tail (deg > 32)
                    int c = __builtin_amdgcn_readfirstlane(col[i]);
                    unsigned uu = X[(long)c * 64 + p];
                    m0 += bflo(uu);
                    m1 += bfhi(uu);
                }
                float inv = 1.f / (float)deg;
                m0 *= inv; m1 *= inv;
            }
            int wi = wswz(r, p);
            Msw[wi] = packbf(m0, m1);
            Ssw[wi] = su;
            b = bn; e = en;
        }
    }
    __syncthreads();
    // ---- MFMA: wave w owns cols [w*16, w*16+16), 2x1 16x16x32 tiles ----
    const int l = t & 63, w = t >> 6;
    const int quad = l >> 4, l15 = l & 15;
    const int wcol = w * 16;
    f32x4 acc[2] = {};
    for (int k0 = 0; k0 < NDIM; k0 += 32) {
        const int kc = k0 + quad * 8;
        short8 ams[2], ass[2], bl, br;
#pragma unroll
        for (int rt = 0; rt < 2; ++rt) {
            int m = rt * 16 + l15;
            ams[rt] = *(const short8*)&Ms[aswz(m, kc)];
            ass[rt] = *(const short8*)&Ss[aswz(m, kc)];
        }
        {
            int n = wcol + l15;
            bl = *(const short8*)&WlT[n * NDIM + kc];
            br = *(const short8*)&WrT[n * NDIM + kc];
        }
#pragma unroll
        for (int rt = 0; rt < 2; ++rt) {
            acc[rt] = __builtin_amdgcn_mfma_f32_16x16x32_bf16(
                ams[rt], bl, acc[rt], 0, 0, 0);
            acc[rt] = __builtin_amdgcn_mfma_f32_16x16x32_bf16(
                ass[rt], br, acc[rt], 0, 0, 0);
        }
    }
    __syncthreads();  // all MFMA LDS reads done; Ms/Ss reusable

    if (OUTMODE == 0) {
        {
            int cg = wcol + l15;
            float bv = biasc[cg];
#pragma unroll
            for (int rt = 0; rt < 2; ++rt)
#pragma unroll
                for (int reg = 0; reg < 4; ++reg) {
                    int row = rt * 16 + quad * 4 + reg;
                    float v = acc[rt][reg] + bv;
                    if (RELU) v = fmaxf(v, 0.f);
                    Ms[row * NDIM + cg] = f2bf(v);
                }
        }
        __syncthreads();
        unsigned* ob = (unsigned*)outp;
        for (int idx = t; idx < MROWS * 64; idx += BTHREADS) {
            int r = idx >> 6;
            if (n0 + r < N) ob[(long)n0 * 64 + idx] = Msw[idx];
        }
    } else {
        {
            int cg = wcol + l15;
            float bv = biasc[cg];
#pragma unroll
            for (int rt = 0; rt < 2; ++rt)
#pragma unroll
                for (int reg = 0; reg < 4; ++reg) {
                    int row = rt * 16 + quad * 4 + reg;
                    float v = acc[rt][reg] + bv;
                    Ms[aswz(row, cg)] = f2bf(v);
                    int n = n0 + row;
                    if (n < N) {
                        if (wf) ((float*)outp)[1 + (long)n * NDIM + cg] = v;
                        else ((__hip_bfloat16*)outp)[1 + (long)n * NDIM + cg] =
                                 __float2bfloat16(v);
                    }
                }
        }
        __syncthreads();
        // ---- decoder GEMM from Abf(Ms) ----
        f32x4 acc2[2] = {};
        for (int k0 = 0; k0 < NDIM; k0 += 32) {
            const int kc = k0 + quad * 8;
            short8 a[2], bwd;
#pragma unroll
            for (int rt = 0; rt < 2; ++rt)
                a[rt] = *(const short8*)&Ms[aswz(rt * 16 + l15, kc)];
            bwd = *(const short8*)&WdT[(wcol + l15) * NDIM + kc];
#pragma unroll
            for (int rt = 0; rt < 2; ++rt)
                acc2[rt] = __builtin_amdgcn_mfma_f32_16x16x32_bf16(
                    a[rt], bwd, acc2[rt], 0, 0, 0);
        }
        float lpos = 0.f, lneg = 0.f;
#pragma unroll
        for (int rt = 0; rt < 2; ++rt)
#pragma unroll
            for (int reg = 0; reg < 4; ++reg) {
                int row = rt * 16 + quad * 4 + reg;
                int yn = ylds[row];
                if (yn >= 0) {
                    float z = acc2[rt][reg];
                    float L = log1pf(expf(-fabsf(z)));
                    if (yn) lpos += fmaxf(-z, 0.f) + L;   // softplus(-z)
                    else    lneg += fmaxf(z, 0.f) + L;    // softplus(z)
                }
            }
#pragma unroll
        for (int off = 32; off >= 1; off >>= 1) {
            lpos += __shfl_down(lpos, off, 64);
            lneg += __shfl_down(lneg, off, 64);
        }
        if (l == 0) { redm[w][0] = lpos; redm[w][1] = lneg; }
        __syncthreads();
        if (t == 0) {
            float sp = 0.f, sn = 0.f;
#pragma unroll
            for (int i = 0; i < 8; ++i) { sp += redm[i][0]; sn += redm[i][1]; }
            atomicAdd(&accum[0], sp);
            atomicAdd(&accum[1], sn);
            int c = 0;
            for (int i = 0; i < MROWS; ++i) if (ylds[i] > 0) c++;
            if (c) atomicAdd(npos, c);
            // ---- folded finalize: last block computes the loss (R12-verified)
            __threadfence();
            unsigned d = (unsigned)atomicAdd(donecnt, 1);
            if (d == (unsigned)(gridDim.x - 1)) {
                float spT = atomicAdd(&accum[0], 0.f);   // coherent reads
                float snT = atomicAdd(&accum[1], 0.f);
                int npv = atomicAdd(npos, 0);
                float np_ = (float)npv;
                float nn_ = (float)N - np_;
                float l2v = spT / (fmaxf(np_, 1.f) * 128.f);
                float l1v = snT / (fmaxf(nn_, 1.f) * 128.f);
                stf(outp, 0, wf, l1v + l2v);
            }
        }
    }
}

// ---- launch ----------------------------------------------------------------

extern "C" void kernel_launch(void* const* d_in, const int* in_sizes, int n_in,
                              void* d_out, int out_size, void* d_ws, size_t ws_size,
                              hipStream_t stream) {
    const void* x    = d_in[0];
    const int* xedge = (const int*)d_in[1];
    const void* y    = d_in[2];
    const void* W1l  = d_in[4];
    const void* b1l  = d_in[5];
    const void* W1r  = d_in[6];
    const void* W2l  = d_in[7];
    const void* b2l  = d_in[8];
    const void* W2r  = d_in[9];
    const void* Wdec = d_in[10];

    const int N = in_sizes[0] / NDIM;
    const int E = in_sizes[1] / 2;

    char* ws = (char*)d_ws;
    size_t off = 0;
    auto alloc = [&](size_t bytes) -> void* {
        void* p = ws + off;
        off = (off + bytes + 255) & ~(size_t)255;
        return p;
    };
    int*   flags  = (int*)alloc(64);
    // cnt | accum | npos | donecnt consecutive: ONE memset zeroes all
    int*   cnt    = (int*)alloc((size_t)N * 4);
    float* accum  = (float*)alloc(64);
    int*   npos   = (int*)alloc(64);
    int*   donecnt= (int*)alloc(64);
    int*   bsum   = (int*)alloc(1024 * 4);
    int*   rowptr = (int*)alloc((size_t)(N + 1) * 4);
    int*   col    = (int*)alloc((size_t)E * 4);
    unsigned* xb  = (unsigned*)alloc((size_t)N * 64 * 4);
    unsigned* hbuf = (unsigned*)alloc((size_t)N * 64 * 4);
    short* T1l = (short*)alloc(NDIM * NDIM * 2);
    short* T1r = (short*)alloc(NDIM * NDIM * 2);
    short* T2l = (short*)alloc(NDIM * NDIM * 2);
    short* T2r = (short*)alloc(NDIM * NDIM * 2);
    short* Td  = (short*)alloc(NDIM * NDIM * 2);
    float* b1c = (float*)alloc(NDIM * 4);
    float* b2c = (float*)alloc(NDIM * 4);

    // zero cnt + accum + npos + donecnt in one shot
    const size_t zlen = (((size_t)N * 4 + 255) & ~(size_t)255) + 3 * 256;
    hipMemsetAsync(cnt, 0, zlen, stream);

    const long prep_items = (E > NDIM * NDIM) ? E : NDIM * NDIM;
    prep_kernel<<<(int)((prep_items + 255) / 256), 256, 0, stream>>>(
        x, W1l, b1l, W1r, W2l, b2l, W2r, Wdec,
        T1l, T1r, T2l, T2r, Td, b1c, b2c, xb, xedge, E, cnt, N, flags);

    const int sb = (N + SCAN_CHUNK - 1) / SCAN_CHUNK;
    scan_partial<<<sb, 256, 0, stream>>>(cnt, bsum, N,
                                         (const unsigned int*)y, flags);
    scan_scatter<<<sb, 256, 0, stream>>>(cnt, bsum, rowptr, N);

    const int eb = (E + 255) / 256;
    fill_kernel<<<eb, 256, 0, stream>>>(xedge, E, flags, cnt, col);

    const int nbM = (N + MROWS - 1) / MROWS;
    // layer 1: reads xb (f32-converted) or x directly (bf16), writes hbuf
    layer_mfma<true, 0><<<nbM, BTHREADS, 0, stream>>>(
        xb, (const unsigned*)x, rowptr, col, T1l, b1c, T1r, nullptr, nullptr,
        flags, hbuf, nullptr, nullptr, nullptr, N);
    // layer 2 (fused): reads hbuf, writes d_out emb + loss (finalize folded)
    layer_mfma<false, 1><<<nbM, BTHREADS, 0, stream>>>(
        hbuf, hbuf, rowptr, col, T2l, b2c, T2r, Td, y, flags,
        d_out, accum, npos, donecnt, N);
}

// Round 15
// 310.625 us; speedup vs baseline: 2.6282x; 1.0978x over previous
//
#include <hip/hip_runtime.h>
#include <hip/hip_bf16.h>

#define NDIM 128
#define MROWS 32           // rows per block (two 16-row MFMA tiles)
#define BTHREADS 512       // 8 waves per block
#define SCAN_CHUNK 1024    // scan: per block 256 threads x 4 elements

typedef __attribute__((ext_vector_type(8))) short short8;
typedef __attribute__((ext_vector_type(4))) float f32x4;

__device__ __forceinline__ float bf2f(__hip_bfloat16 v) { return __bfloat162float(v); }

__device__ __forceinline__ float ldf(const void* p, long i, int f32) {
    return f32 ? ((const float*)p)[i] : bf2f(((const __hip_bfloat16*)p)[i]);
}
__device__ __forceinline__ void stf(void* p, long i, int f32, float v) {
    if (f32) ((float*)p)[i] = v;
    else     ((__hip_bfloat16*)p)[i] = __float2bfloat16(v);
}
__device__ __forceinline__ short f2bf(float v) {
    __hip_bfloat16 h = __float2bfloat16(v);
    short s;
    __builtin_memcpy(&s, &h, 2);
    return s;
}
// bf16x2 packed in a uint: low halfword = even feature, high = odd feature
__device__ __forceinline__ float bflo(unsigned u) { u <<= 16; float f; __builtin_memcpy(&f, &u, 4); return f; }
__device__ __forceinline__ float bfhi(unsigned u) { u &= 0xffff0000u; float f; __builtin_memcpy(&f, &u, 4); return f; }
__device__ __forceinline__ unsigned packbf(float a, float b) {
    unsigned la = (unsigned short)f2bf(a);
    unsigned hb = (unsigned short)f2bf(b);
    return (hb << 16) | la;
}
// Swizzled LDS index (shorts) for A-tiles: 16B-chunk XOR by (row&7).
__device__ __forceinline__ int aswz(int m, int k) {
    return m * NDIM + ((((k >> 3) ^ (m & 7)) << 3) | (k & 7));
}
// Same swizzle at uint (bf16x2) granularity: p = feature-pair index 0..63.
__device__ __forceinline__ int wswz(int m, int p) {
    return m * 64 + ((((p >> 2) ^ (m & 7)) << 2) | (p & 3));
}

// asm-pinned gather load: result VGPR stays allocated and the load cannot be
// sunk into its consumer (R5-R8: every source-level pipeline collapsed;
// VGPR=32 proved it). R9/R11 verified this structure passing at 75us.
#define GLOAD(dst, sa, voff)                                              \
    asm volatile("global_load_dword %0, %1, %2"                           \
                 : "=v"(dst) : "v"(voff), "s"(sa) : "memory")

// ---- prep: per-block dtype detection + weights + biases + degree pass ------

__global__ void prep_kernel(const void* __restrict__ x,
                            const void* __restrict__ W1l, const void* __restrict__ b1l,
                            const void* __restrict__ W1r, const void* __restrict__ W2l,
                            const void* __restrict__ b2l, const void* __restrict__ W2r,
                            const void* __restrict__ Wd,
                            short* __restrict__ T1l, short* __restrict__ T1r,
                            short* __restrict__ T2l, short* __restrict__ T2r,
                            short* __restrict__ Td, float* __restrict__ b1c,
                            float* __restrict__ b2c, unsigned* __restrict__ xb,
                            const int* __restrict__ xedge, int E,
                            int* __restrict__ cnt, int N,
                            int* __restrict__ flags) {
    __shared__ int s_se, s_sc;
    const int t = threadIdx.x;
    if (t == 0) { s_se = 1; s_sc = 0; }
    __syncthreads();
    {
        for (int i = t; i < 512; i += 256)
            if (xedge[2 * i + 1] != 0) s_se = 0;
        const unsigned short* xh = (const unsigned short*)x;
        int c = 0;
        for (int i = t; i < 1024; i += 256) {
            int ex = (xh[2 * i] >> 7) & 0xFF;
            if (ex >= 100 && ex <= 150) c++;
        }
        atomicAdd(&s_sc, c);
    }
    __syncthreads();
    const int e64 = s_se;
    const int wf = (s_sc < 900) ? 1 : 0;
    if (blockIdx.x == 0 && t == 0) {
        flags[0] = e64;
        flags[2] = wf;
    }
    const long idx = (long)blockIdx.x * 256 + t;
    if (idx < E) {
        int d = e64 ? xedge[2 * (E + idx)] : xedge[E + idx];
        atomicAdd(&cnt[d], 1);
    }
    if (idx < NDIM * NDIM) {
        int k = (int)(idx >> 7), n = (int)(idx & 127);
        int o = n * NDIM + k;
        T1l[o] = f2bf(ldf(W1l, idx, wf));
        T1r[o] = f2bf(ldf(W1r, idx, wf));
        T2l[o] = f2bf(ldf(W2l, idx, wf));
        T2r[o] = f2bf(ldf(W2r, idx, wf));
        Td [o] = f2bf(ldf(Wd , idx, wf));
        if (idx < NDIM) { b1c[idx] = ldf(b1l, idx, wf); b2c[idx] = ldf(b2l, idx, wf); }
    }
    if (wf) {
        const long np = (long)N * 64;
        const long stride = (long)gridDim.x * 256;
        for (long pidx = idx; pidx < np; pidx += stride) {
            float2 v = ((const float2*)x)[pidx];
            xb[pidx] = packbf(v.x, v.y);
        }
    }
}

// ---- 2-kernel exclusive scan: partial sums, then scatter with self-prefix --
// (scan_bsums eliminated: each scatter block sums bsum[0..blockIdx) itself —
// <=49 ints, L2-broadcast. y-dtype probe folded into scan_partial block 0.)

__global__ void scan_partial(const int* __restrict__ cnt, int* __restrict__ bsum, int N,
                             const unsigned int* __restrict__ yw,
                             int* __restrict__ flags) {
    __shared__ int red[256];
    const int t = threadIdx.x;
    if (blockIdx.x == 0) {
        __shared__ int s_sy;
        if (t == 0) s_sy = 0;
        __syncthreads();
        for (int i = t; i < 1024; i += 256)
            if (yw[i] > 1u) s_sy = 1;
        __syncthreads();
        if (t == 0) flags[1] = s_sy;
    }
    const long base = (long)blockIdx.x * SCAN_CHUNK + (long)t * 4;
    int s = 0;
#pragma unroll
    for (int i = 0; i < 4; ++i) { long idx = base + i; if (idx < N) s += cnt[idx]; }
    red[t] = s;
    __syncthreads();
    for (int off = 128; off >= 1; off >>= 1) {
        if (t < off) red[t] += red[t + off];
        __syncthreads();
    }
    if (t == 0) bsum[blockIdx.x] = red[0];
}

__global__ void scan_scatter(int* __restrict__ cnt, const int* __restrict__ bsum,
                             int* __restrict__ rowptr, int N) {
    __shared__ int tsum[256];
    __shared__ int red[256];
    const int t = threadIdx.x;
    const long base = (long)blockIdx.x * SCAN_CHUNK + (long)t * 4;
    int loc[4];
    int s = 0;
#pragma unroll
    for (int i = 0; i < 4; ++i) {
        long idx = base + i;
        int c = (idx < N) ? cnt[idx] : 0;
        loc[i] = s;
        s += c;
    }
    tsum[t] = s;
    // self-prefix over previous blocks' sums
    int sown = 0;
    for (int i = t; i < blockIdx.x; i += 256) sown += bsum[i];
    red[t] = sown;
    __syncthreads();
    for (int off = 1; off < 256; off <<= 1) {
        int u = (t >= off) ? tsum[t - off] : 0;
        __syncthreads();
        tsum[t] += u;
        __syncthreads();
    }
    for (int off = 128; off >= 1; off >>= 1) {
        if (t < off) red[t] += red[t + off];
        __syncthreads();
    }
    const int b0 = red[0];
    const int texcl = tsum[t] - s;
#pragma unroll
    for (int i = 0; i < 4; ++i) {
        long idx = base + i;
        if (idx < N) {
            int v = b0 + texcl + loc[i];
            rowptr[idx] = v;
            cnt[idx] = v;   // cursor seed for fill
        }
    }
    if (blockIdx.x == gridDim.x - 1 && t == 255) rowptr[N] = b0 + tsum[255];
}

__global__ void fill_kernel(const int* __restrict__ xedge, int E,
                            const int* __restrict__ flags,
                            int* __restrict__ cur, int* __restrict__ col) {
    int e = blockIdx.x * blockDim.x + threadIdx.x;
    if (e >= E) return;
    const int e64 = flags[0];
    int s = e64 ? xedge[2 * e] : xedge[e];
    int d = e64 ? xedge[2 * (E + e)] : xedge[E + e];
    int p = atomicAdd(&cur[d], 1);
    col[p] = s;
}

// ---- SAGE layer: 32-row blocks, 8 waves, 4 rows/wave. (R9/R11 verified)
// Gather: a row's X-loads (deg-gated groups of 8 + self row) issued as
// inline-asm global_load_dword (SGPR row base + VGPR lane offset), ONE
// s_waitcnt vmcnt(0) per row, pass-through asm on each result, then the
// exact masked-add tree. Scalar col loads (wave-uniform base), clamped.
// ORDERING: the rowptr prefetch (compiler-tracked load) issues AND is
// consumed BEFORE the asm window, so no compiler vmcnt wait lands inside.
// OUTMODE 0: bf16 out (outp=hbuf). OUTMODE 1: fused emb store + decoder
// MFMA + BCE loss. Xb = converted bf16x2 (wf==1); Xraw = raw bf16 (wf==0).

template <bool RELU, int OUTMODE>
__global__ __launch_bounds__(BTHREADS, 2)
void layer_mfma(const unsigned* __restrict__ Xb, const unsigned* __restrict__ Xraw,
                const int* __restrict__ rowptr,
                const int* __restrict__ col, const short* __restrict__ WlT,
                const float* __restrict__ biasc, const short* __restrict__ WrT,
                const short* __restrict__ WdT, const void* __restrict__ yv,
                const int* __restrict__ flags, void* __restrict__ outp,
                float* __restrict__ accum, int* __restrict__ npos, int N) {
    __shared__ short AS[2 * MROWS * NDIM];  // [Ms 8KB][Ss 8KB]
    __shared__ int ylds[MROWS];
    __shared__ float redm[8][2];
    short* Ms = AS;
    short* Ss = AS + MROWS * NDIM;
    unsigned* Msw = (unsigned*)Ms;
    unsigned* Ssw = (unsigned*)Ss;
    const int t = threadIdx.x;
    const int n0 = blockIdx.x * MROWS;
    const int wf = flags[2];
    const unsigned* __restrict__ X = wf ? Xb : Xraw;

    if (OUTMODE == 1 && t < MROWS) {
        const int yb = flags[1];
        int n = n0 + t;
        int yn = -1;
        if (n < N)
            yn = yb ? (int)((const unsigned char*)yv)[n]
                    : (((const int*)yv)[n] != 0 ? 1 : 0);
        ylds[t] = yn;
    }

    // ---- gather: 8 row-groups (one wave each), 4 rows/wave ------------------
    {
        const int p = t & 63;
        const unsigned voff = (unsigned)(p * 4);
        const unsigned long long Xb64 = (unsigned long long)(uintptr_t)X;
        const int g = __builtin_amdgcn_readfirstlane(t >> 6);
        int r = g;
        // prologue: first row's rowptr
        int b = 0, e = 0;
        {
            int n = n0 + r;
            if (n < N) {
                b = __builtin_amdgcn_readfirstlane(rowptr[n]);
                e = __builtin_amdgcn_readfirstlane(rowptr[n + 1]);
            }
        }
        for (int it = 0; it < 4; ++it, r += 8) {
            const int n = n0 + r;
            const int deg = e - b;
            // scalar col loads (wave-uniform base), grouped by 8, clamped so
            // garbage beyond deg can't form wild addresses.
            const int* colb = col + b;
            int cs[32];
            if (deg > 0) {
#pragma unroll
                for (int j = 0; j < 8; ++j) {
                    int c = __builtin_amdgcn_readfirstlane(colb[j]);
                    cs[j] = ((unsigned)c >= (unsigned)N) ? 0 : c;
                }
            }
            if (deg > 8) {
#pragma unroll
                for (int j = 8; j < 16; ++j) {
                    int c = __builtin_amdgcn_readfirstlane(colb[j]);
                    cs[j] = ((unsigned)c >= (unsigned)N) ? 0 : c;
                }
            }
            if (deg > 16) {
#pragma unroll
                for (int j = 16; j < 24; ++j) {
                    int c = __builtin_amdgcn_readfirstlane(colb[j]);
                    cs[j] = ((unsigned)c >= (unsigned)N) ? 0 : c;
                }
            }
            if (deg > 24) {
#pragma unroll
                for (int j = 24; j < 32; ++j) {
                    int c = __builtin_amdgcn_readfirstlane(colb[j]);
                    cs[j] = ((unsigned)c >= (unsigned)N) ? 0 : c;
                }
            }
            // rowptr prefetch: compiler-tracked load, consumed NOW (before the
            // asm window) so its implicit wait can't drain our pinned loads.
            int bn = 0, en = 0;
            if (it < 3) {
                int nn = n0 + r + 8;
                if (nn < N) {
                    bn = __builtin_amdgcn_readfirstlane(rowptr[nn]);
                    en = __builtin_amdgcn_readfirstlane(rowptr[nn + 1]);
                }
            }
            // ---- issue ALL loads (asm-pinned; results stay in VGPRs) ----
            unsigned u[32];
            unsigned su = 0;
            if (n < N) {
                unsigned long long sa = Xb64 + ((unsigned long long)(unsigned)n << 8);
                GLOAD(su, sa, voff);
            }
            if (deg > 0) {
#pragma unroll
                for (int j = 0; j < 8; ++j) {
                    unsigned long long sa = Xb64 + ((unsigned long long)(unsigned)cs[j] << 8);
                    GLOAD(u[j], sa, voff);
                }
            }
            if (deg > 8) {
#pragma unroll
                for (int j = 8; j < 16; ++j) {
                    unsigned long long sa = Xb64 + ((unsigned long long)(unsigned)cs[j] << 8);
                    GLOAD(u[j], sa, voff);
                }
            }
            if (deg > 16) {
#pragma unroll
                for (int j = 16; j < 24; ++j) {
                    unsigned long long sa = Xb64 + ((unsigned long long)(unsigned)cs[j] << 8);
                    GLOAD(u[j], sa, voff);
                }
            }
            if (deg > 24) {
#pragma unroll
                for (int j = 24; j < 32; ++j) {
                    unsigned long long sa = Xb64 + ((unsigned long long)(unsigned)cs[j] << 8);
                    GLOAD(u[j], sa, voff);
                }
            }
            // ---- ONE drain for the whole row ----
            asm volatile("s_waitcnt vmcnt(0)" ::: "memory");
            __builtin_amdgcn_sched_barrier(0);
            // pass-through asm: consumption data-depends on post-wait defs
            if (n < N) asm volatile("" : "+v"(su));
            if (deg > 0) {
#pragma unroll
                for (int j = 0; j < 8; ++j) asm volatile("" : "+v"(u[j]));
            }
            if (deg > 8) {
#pragma unroll
                for (int j = 8; j < 16; ++j) asm volatile("" : "+v"(u[j]));
            }
            if (deg > 16) {
#pragma unroll
                for (int j = 16; j < 24; ++j) asm volatile("" : "+v"(u[j]));
            }
            if (deg > 24) {
#pragma unroll
                for (int j = 24; j < 32; ++j) asm volatile("" : "+v"(u[j]));
            }
            // ---- exact masked 8-way partial-sum tree (same order as R4-R9) --
            float m0 = 0.f, m1 = 0.f;
            if (deg > 0) {
                float p0 = 0.f, p1 = 0.f, p2 = 0.f, p3 = 0.f;
                float q0 = 0.f, q1 = 0.f, q2 = 0.f, q3 = 0.f;
#pragma unroll
                for (int j = 0; j < 32; j += 4) {
                    if (j + 0 < deg) { p0 += bflo(u[j]);     q0 += bfhi(u[j]); }
                    if (j + 1 < deg) { p1 += bflo(u[j + 1]); q1 += bfhi(u[j + 1]); }
                    if (j + 2 < deg) { p2 += bflo(u[j + 2]); q2 += bfhi(u[j + 2]); }
                    if (j + 3 < deg) { p3 += bflo(u[j + 3]); q3 += bfhi(u[j + 3]); }
                }
                m0 = (p0 + p1) + (p2 + p3);
                m1 = (q0 + q1) + (q2 + q3);
                for (int i = b + 32; i < e; ++i) {  // rare tail (deg > 32)
                    int c = __builtin_amdgcn_readfirstlane(col[i]);
                    unsigned uu = X[(long)c * 64 + p];
                    m0 += bflo(uu);
                    m1 += bfhi(uu);
                }
                float inv = 1.f / (float)deg;
                m0 *= inv; m1 *= inv;
            }
            int wi = wswz(r, p);
            Msw[wi] = packbf(m0, m1);
            Ssw[wi] = su;
            b = bn; e = en;
        }
    }
    __syncthreads();
    // ---- MFMA: wave w owns cols [w*16, w*16+16), 2x1 16x16x32 tiles ----
    const int l = t & 63, w = t >> 6;
    const int quad = l >> 4, l15 = l & 15;
    const int wcol = w * 16;
    f32x4 acc[2] = {};
    for (int k0 = 0; k0 < NDIM; k0 += 32) {
        const int kc = k0 + quad * 8;
        short8 ams[2], ass[2], bl, br;
#pragma unroll
        for (int rt = 0; rt < 2; ++rt) {
            int m = rt * 16 + l15;
            ams[rt] = *(const short8*)&Ms[aswz(m, kc)];
            ass[rt] = *(const short8*)&Ss[aswz(m, kc)];
        }
        {
            int n = wcol + l15;
            bl = *(const short8*)&WlT[n * NDIM + kc];
            br = *(const short8*)&WrT[n * NDIM + kc];
        }
#pragma unroll
        for (int rt = 0; rt < 2; ++rt) {
            acc[rt] = __builtin_amdgcn_mfma_f32_16x16x32_bf16(
                ams[rt], bl, acc[rt], 0, 0, 0);
            acc[rt] = __builtin_amdgcn_mfma_f32_16x16x32_bf16(
                ass[rt], br, acc[rt], 0, 0, 0);
        }
    }
    __syncthreads();  // all MFMA LDS reads done; Ms/Ss reusable

    if (OUTMODE == 0) {
        // bf16 out tile row-major in Ms region, then coalesced uint store
        {
            int cg = wcol + l15;
            float bv = biasc[cg];
#pragma unroll
            for (int rt = 0; rt < 2; ++rt)
#pragma unroll
                for (int reg = 0; reg < 4; ++reg) {
                    int row = rt * 16 + quad * 4 + reg;
                    float v = acc[rt][reg] + bv;
                    if (RELU) v = fmaxf(v, 0.f);
                    Ms[row * NDIM + cg] = f2bf(v);
                }
        }
        __syncthreads();
        unsigned* ob = (unsigned*)outp;
        for (int idx = t; idx < MROWS * 64; idx += BTHREADS) {
            int r = idx >> 6;
            if (n0 + r < N) ob[(long)n0 * 64 + idx] = Msw[idx];
        }
    } else {
        // ---- fused: Abf into Ms (aswz) + direct emb store from registers ----
        {
            int cg = wcol + l15;
            float bv = biasc[cg];
#pragma unroll
            for (int rt = 0; rt < 2; ++rt)
#pragma unroll
                for (int reg = 0; reg < 4; ++reg) {
                    int row = rt * 16 + quad * 4 + reg;
                    float v = acc[rt][reg] + bv;
                    Ms[aswz(row, cg)] = f2bf(v);
                    int n = n0 + row;
                    if (n < N) {
                        if (wf) ((float*)outp)[1 + (long)n * NDIM + cg] = v;
                        else ((__hip_bfloat16*)outp)[1 + (long)n * NDIM + cg] =
                                 __float2bfloat16(v);
                    }
                }
        }
        __syncthreads();
        // ---- decoder GEMM from Abf(Ms) ----
        f32x4 acc2[2] = {};
        for (int k0 = 0; k0 < NDIM; k0 += 32) {
            const int kc = k0 + quad * 8;
            short8 a[2], bwd;
#pragma unroll
            for (int rt = 0; rt < 2; ++rt)
                a[rt] = *(const short8*)&Ms[aswz(rt * 16 + l15, kc)];
            bwd = *(const short8*)&WdT[(wcol + l15) * NDIM + kc];
#pragma unroll
            for (int rt = 0; rt < 2; ++rt)
                acc2[rt] = __builtin_amdgcn_mfma_f32_16x16x32_bf16(
                    a[rt], bwd, acc2[rt], 0, 0, 0);
        }
        float lpos = 0.f, lneg = 0.f;
#pragma unroll
        for (int rt = 0; rt < 2; ++rt)
#pragma unroll
            for (int reg = 0; reg < 4; ++reg) {
                int row = rt * 16 + quad * 4 + reg;
                int yn = ylds[row];
                if (yn >= 0) {
                    float z = acc2[rt][reg];
                    float L = log1pf(expf(-fabsf(z)));
                    if (yn) lpos += fmaxf(-z, 0.f) + L;   // softplus(-z)
                    else    lneg += fmaxf(z, 0.f) + L;    // softplus(z)
                }
            }
#pragma unroll
        for (int off = 32; off >= 1; off >>= 1) {
            lpos += __shfl_down(lpos, off, 64);
            lneg += __shfl_down(lneg, off, 64);
        }
        if (l == 0) { redm[w][0] = lpos; redm[w][1] = lneg; }
        __syncthreads();
        if (t == 0) {
            float sp = 0.f, sn = 0.f;
#pragma unroll
            for (int i = 0; i < 8; ++i) { sp += redm[i][0]; sn += redm[i][1]; }
            atomicAdd(&accum[0], sp);
            atomicAdd(&accum[1], sn);
            int c = 0;
            for (int i = 0; i < MROWS; ++i) if (ylds[i] > 0) c++;
            if (c) atomicAdd(npos, c);
        }
    }
}

__global__ void finalize_kernel(const float* __restrict__ accum, const int* __restrict__ npos,
                                const int* __restrict__ flags, void* __restrict__ out, int N) {
    float np_ = (float)(*npos);
    float nn_ = (float)N - np_;
    float l2 = accum[0] / (fmaxf(np_, 1.f) * 128.f);
    float l1 = accum[1] / (fmaxf(nn_, 1.f) * 128.f);
    stf(out, 0, flags[2], l1 + l2);
}

// ---- launch ----------------------------------------------------------------

extern "C" void kernel_launch(void* const* d_in, const int* in_sizes, int n_in,
                              void* d_out, int out_size, void* d_ws, size_t ws_size,
                              hipStream_t stream) {
    const void* x    = d_in[0];
    const int* xedge = (const int*)d_in[1];
    const void* y    = d_in[2];
    const void* W1l  = d_in[4];
    const void* b1l  = d_in[5];
    const void* W1r  = d_in[6];
    const void* W2l  = d_in[7];
    const void* b2l  = d_in[8];
    const void* W2r  = d_in[9];
    const void* Wdec = d_in[10];

    const int N = in_sizes[0] / NDIM;
    const int E = in_sizes[1] / 2;

    char* ws = (char*)d_ws;
    size_t off = 0;
    auto alloc = [&](size_t bytes) -> void* {
        void* p = ws + off;
        off = (off + bytes + 255) & ~(size_t)255;
        return p;
    };
    int*   flags  = (int*)alloc(64);
    // cnt | accum | npos are consecutive: zeroed with ONE memset
    int*   cnt    = (int*)alloc((size_t)N * 4);
    float* accum  = (float*)alloc(64);
    int*   npos   = (int*)alloc(64);
    int*   bsum   = (int*)alloc(1024 * 4);
    int*   rowptr = (int*)alloc((size_t)(N + 1) * 4);
    int*   col    = (int*)alloc((size_t)E * 4);
    unsigned* xb  = (unsigned*)alloc((size_t)N * 64 * 4);
    unsigned* hbuf = (unsigned*)alloc((size_t)N * 64 * 4);
    short* T1l = (short*)alloc(NDIM * NDIM * 2);
    short* T1r = (short*)alloc(NDIM * NDIM * 2);
    short* T2l = (short*)alloc(NDIM * NDIM * 2);
    short* T2r = (short*)alloc(NDIM * NDIM * 2);
    short* Td  = (short*)alloc(NDIM * NDIM * 2);
    float* b1c = (float*)alloc(NDIM * 4);
    float* b2c = (float*)alloc(NDIM * 4);

    const size_t zlen = (((size_t)N * 4 + 255) & ~(size_t)255) + 512;
    hipMemsetAsync(cnt, 0, zlen, stream);   // cnt + accum + npos in one shot

    const long prep_items = (E > NDIM * NDIM) ? E : NDIM * NDIM;
    prep_kernel<<<(int)((prep_items + 255) / 256), 256, 0, stream>>>(
        x, W1l, b1l, W1r, W2l, b2l, W2r, Wdec,
        T1l, T1r, T2l, T2r, Td, b1c, b2c, xb, xedge, E, cnt, N, flags);

    const int sb = (N + SCAN_CHUNK - 1) / SCAN_CHUNK;
    scan_partial<<<sb, 256, 0, stream>>>(cnt, bsum, N, (const unsigned int*)y, flags);
    scan_scatter<<<sb, 256, 0, stream>>>(cnt, bsum, rowptr, N);

    const int eb = (E + 255) / 256;
    fill_kernel<<<eb, 256, 0, stream>>>(xedge, E, flags, cnt, col);

    const int nbM = (N + MROWS - 1) / MROWS;
    // layer 1: reads xb (f32-converted) or x directly (bf16), writes hbuf
    layer_mfma<true, 0><<<nbM, BTHREADS, 0, stream>>>(
        xb, (const unsigned*)x, rowptr, col, T1l, b1c, T1r, nullptr, nullptr,
        flags, hbuf, nullptr, nullptr, N);
    // layer 2 (fused): reads hbuf, writes d_out emb + loss partials
    layer_mfma<false, 1><<<nbM, BTHREADS, 0, stream>>>(
        hbuf, hbuf, rowptr, col, T2l, b2c, T2r, Td, y, flags,
        d_out, accum, npos, N);
    finalize_kernel<<<1, 1, 0, stream>>>(accum, npos, flags, d_out, N);
}